// Round 1
// baseline (399.572 us; speedup 1.0000x reference)
//
#include <hip/hip_runtime.h>

#define BATCH 65536
#define DIM 512
#define NCLS 100
#define ALPHA 0.5f

#define RPB 512      // rows per block (main kernel)
#define SLICE 128    // dims per slice (DIM/4)
#define MAIN_THREADS 512

// ---------------------------------------------------------------------------
// Kernel A: extract labels from one-hot + histogram counts.
// onehot is [BATCH, 100] f32, exactly one 1.0 per row. Flat float4 scan.
// ---------------------------------------------------------------------------
__global__ void labels_kernel(const float* __restrict__ onehot,
                              int* __restrict__ labels,
                              int* __restrict__ counts) {
    const int i4 = blockIdx.x * blockDim.x + threadIdx.x;   // float4 index
    const float4 v = reinterpret_cast<const float4*>(onehot)[i4];
    const int base = i4 * 4;
    float vals[4] = {v.x, v.y, v.z, v.w};
#pragma unroll
    for (int k = 0; k < 4; ++k) {
        if (vals[k] > 0.5f) {
            const int e = base + k;
            const int b = e / NCLS;
            const int c = e - b * NCLS;
            labels[b] = c;                 // exactly one writer per row
            atomicAdd(&counts[c], 1);
        }
    }
}

// ---------------------------------------------------------------------------
// Kernel B: per-row squared distance + per-class diff scatter (LDS staged).
// grid = (BATCH/RPB, DIM/SLICE), block = 512 threads.
// Each 32-lane group handles one row's 128-dim slice via float4.
// ---------------------------------------------------------------------------
__global__ void __launch_bounds__(MAIN_THREADS, 2)
main_kernel(const float* __restrict__ features,
            const float* __restrict__ centers,
            const int* __restrict__ labels,
            float* __restrict__ delta,     // [NCLS][DIM] global accumulator (pre-zeroed)
            float* __restrict__ result) {  // [BATCH] (pre-zeroed)
    __shared__ float acc[NCLS * SLICE];    // 51.2 KB
    __shared__ int lab[RPB];               // 2 KB

    const int t = threadIdx.x;
    const int r0 = blockIdx.x * RPB;
    const int slice = blockIdx.y;

    for (int j = t; j < NCLS * SLICE; j += MAIN_THREADS) acc[j] = 0.0f;
    if (t < RPB) lab[t] = labels[r0 + t];
    __syncthreads();

    const int lane = t & 31;               // dim group within slice
    const int rsub = t >> 5;               // 0..15: row-in-flight index
    const int d0 = slice * SLICE + lane * 4;

    for (int i = 0; i < RPB; i += MAIN_THREADS / 32) {
        const int rl = i + rsub;
        const int row = r0 + rl;
        const int lb = lab[rl];
        const float4 f = *reinterpret_cast<const float4*>(&features[row * DIM + d0]);
        const float4 c = *reinterpret_cast<const float4*>(&centers[lb * DIM + d0]);
        const float dx = c.x - f.x;
        const float dy = c.y - f.y;
        const float dz = c.z - f.z;
        const float dw = c.w - f.w;

        // squared-distance partial: reduce across the 32 lanes of this row
        float sq = dx * dx + dy * dy + dz * dz + dw * dw;
#pragma unroll
        for (int m = 16; m >= 1; m >>= 1) sq += __shfl_xor(sq, m);
        if (lane == 0) unsafeAtomicAdd(&result[row], sq);

        // per-class diff accumulation in LDS (ds_add_f32)
        float* a = &acc[lb * SLICE + lane * 4];
        atomicAdd(a + 0, dx);
        atomicAdd(a + 1, dy);
        atomicAdd(a + 2, dz);
        atomicAdd(a + 3, dw);
    }
    __syncthreads();

    // merge LDS partial into the global delta accumulator
    for (int j = t; j < NCLS * SLICE; j += MAIN_THREADS) {
        const int c = j >> 7;              // j / SLICE
        const int d = j & (SLICE - 1);     // j % SLICE
        unsafeAtomicAdd(&delta[c * DIM + slice * SLICE + d], acc[j]);
    }
}

// ---------------------------------------------------------------------------
// Kernel C: new_centers = centers - ALPHA * delta / (count + 1)
// ---------------------------------------------------------------------------
__global__ void finalize_kernel(const float* __restrict__ centers,
                                const float* __restrict__ delta,
                                const int* __restrict__ counts,
                                float* __restrict__ new_centers) {
    const int idx = blockIdx.x * blockDim.x + threadIdx.x;
    if (idx >= NCLS * DIM) return;
    const int c = idx / DIM;
    const float cnt = (float)counts[c] + 1.0f;
    new_centers[idx] = centers[idx] - ALPHA * (delta[idx] / cnt);
}

extern "C" void kernel_launch(void* const* d_in, const int* in_sizes, int n_in,
                              void* d_out, int out_size, void* d_ws, size_t ws_size,
                              hipStream_t stream) {
    const float* features = (const float*)d_in[0];   // [65536, 512]
    const float* onehot   = (const float*)d_in[1];   // [65536, 100]
    const float* centers  = (const float*)d_in[2];   // [100, 512]

    float* result      = (float*)d_out;              // [65536]
    float* new_centers = (float*)d_out + BATCH;      // [100*512]

    char* ws = (char*)d_ws;
    float* delta = (float*)ws;                              // 51200 f32
    int*   counts = (int*)(ws + NCLS * DIM * sizeof(float)); // 128 ints
    int*   labels = (int*)(ws + NCLS * DIM * sizeof(float) + 128 * sizeof(int)); // 65536 ints

    hipMemsetAsync(result, 0, BATCH * sizeof(float), stream);
    hipMemsetAsync(delta, 0, NCLS * DIM * sizeof(float), stream);
    hipMemsetAsync(counts, 0, 128 * sizeof(int), stream);

    labels_kernel<<<(BATCH * NCLS / 4) / 256, 256, 0, stream>>>(onehot, labels, counts);

    dim3 grid(BATCH / RPB, DIM / SLICE);
    main_kernel<<<grid, MAIN_THREADS, 0, stream>>>(features, centers, labels, delta, result);

    finalize_kernel<<<(NCLS * DIM + 255) / 256, 256, 0, stream>>>(centers, delta, counts, new_centers);
}

// Round 2
// 273.075 us; speedup vs baseline: 1.4632x; 1.4632x over previous
//
#include <hip/hip_runtime.h>

#define BATCH 65536
#define DIM 512
#define NCLS 100
#define ALPHA 0.5f

#define CAP 1024            // per-class slot capacity (max multinomial count ~780 for B=65536,C=100)
#define CHUNKS 8            // blocks per class in delta_kernel
#define CBLOCK 256          // threads per block (4 waves)
#define SLOTS (CHUNKS * (CBLOCK / 64))   // 32 wave-slots per class

// ---------------------------------------------------------------------------
// Kernel A: scan one-hot, bucket row indices by class (counting-sort scatter).
// onehot is [BATCH, 100] f32, exactly one 1.0 per row.
// ---------------------------------------------------------------------------
__global__ void scatter_kernel(const float* __restrict__ onehot,
                               int* __restrict__ counts,
                               int* __restrict__ order) {
    const int i4 = blockIdx.x * blockDim.x + threadIdx.x;   // float4 index
    const float4 v = reinterpret_cast<const float4*>(onehot)[i4];
    const int base = i4 * 4;
    const float vals[4] = {v.x, v.y, v.z, v.w};
#pragma unroll
    for (int k = 0; k < 4; ++k) {
        if (vals[k] > 0.5f) {
            const int e = base + k;
            const int b = e / NCLS;
            const int c = e - b * NCLS;
            const int rank = atomicAdd(&counts[c], 1);
            order[c * CAP + rank] = b;
        }
    }
}

// ---------------------------------------------------------------------------
// Kernel B: fused squared-distance + per-class feature-sum.
// grid = (CHUNKS, NCLS), block = 256 (4 waves). Each wave processes rows of
// ONE class; lane owns dims [lane*8, lane*8+8). Register accumulation only.
// delta[c] = cnt_c * center_c - sum_{b in c} f_b  (computed in finalize).
// ---------------------------------------------------------------------------
__global__ void __launch_bounds__(CBLOCK)
delta_kernel(const float* __restrict__ features,
             const float* __restrict__ centers,
             const int* __restrict__ order,
             const int* __restrict__ counts,
             float* __restrict__ sumf,      // [NCLS][DIM], pre-zeroed
             float* __restrict__ result) {  // [BATCH], each row written once
    const int c = blockIdx.y;
    const int cnt = counts[c];
    const int lane = threadIdx.x & 63;
    const int wave = threadIdx.x >> 6;
    const int slot = blockIdx.x * (CBLOCK / 64) + wave;   // 0..SLOTS-1
    const int d = lane * 8;

    const float4 c0 = *reinterpret_cast<const float4*>(&centers[c * DIM + d]);
    const float4 c1 = *reinterpret_cast<const float4*>(&centers[c * DIM + d + 4]);
    float4 sA = make_float4(0.f, 0.f, 0.f, 0.f);
    float4 sB = make_float4(0.f, 0.f, 0.f, 0.f);

    const int* ord = &order[c * CAP];
    for (int i = slot; i < cnt; i += SLOTS) {
        const int b = ord[i];
        const float4 f0 = *reinterpret_cast<const float4*>(&features[b * DIM + d]);
        const float4 f1 = *reinterpret_cast<const float4*>(&features[b * DIM + d + 4]);

        sA.x += f0.x; sA.y += f0.y; sA.z += f0.z; sA.w += f0.w;
        sB.x += f1.x; sB.y += f1.y; sB.z += f1.z; sB.w += f1.w;

        const float dx0 = f0.x - c0.x, dy0 = f0.y - c0.y;
        const float dz0 = f0.z - c0.z, dw0 = f0.w - c0.w;
        const float dx1 = f1.x - c1.x, dy1 = f1.y - c1.y;
        const float dz1 = f1.z - c1.z, dw1 = f1.w - c1.w;
        float sq = dx0 * dx0 + dy0 * dy0 + dz0 * dz0 + dw0 * dw0
                 + dx1 * dx1 + dy1 * dy1 + dz1 * dz1 + dw1 * dw1;
#pragma unroll
        for (int m = 32; m >= 1; m >>= 1) sq += __shfl_xor(sq, m);
        if (lane == 0) result[b] = sq;
    }

    // merge this wave's partial feature-sum (8 atomics per lane, L2-resident)
    float* dst = &sumf[c * DIM + d];
    unsafeAtomicAdd(dst + 0, sA.x);
    unsafeAtomicAdd(dst + 1, sA.y);
    unsafeAtomicAdd(dst + 2, sA.z);
    unsafeAtomicAdd(dst + 3, sA.w);
    unsafeAtomicAdd(dst + 4, sB.x);
    unsafeAtomicAdd(dst + 5, sB.y);
    unsafeAtomicAdd(dst + 6, sB.z);
    unsafeAtomicAdd(dst + 7, sB.w);
}

// ---------------------------------------------------------------------------
// Kernel C: new_centers = centers - ALPHA * (cnt*center - sumf) / (cnt + 1)
// ---------------------------------------------------------------------------
__global__ void finalize_kernel(const float* __restrict__ centers,
                                const float* __restrict__ sumf,
                                const int* __restrict__ counts,
                                float* __restrict__ new_centers) {
    const int idx = blockIdx.x * blockDim.x + threadIdx.x;
    if (idx >= NCLS * DIM) return;
    const int c = idx >> 9;                 // / DIM
    const float cntf = (float)counts[c];
    const float ctr = centers[idx];
    const float delta = (cntf * ctr - sumf[idx]) / (cntf + 1.0f);
    new_centers[idx] = ctr - ALPHA * delta;
}

extern "C" void kernel_launch(void* const* d_in, const int* in_sizes, int n_in,
                              void* d_out, int out_size, void* d_ws, size_t ws_size,
                              hipStream_t stream) {
    const float* features = (const float*)d_in[0];   // [65536, 512]
    const float* onehot   = (const float*)d_in[1];   // [65536, 100]
    const float* centers  = (const float*)d_in[2];   // [100, 512]

    float* result      = (float*)d_out;              // [65536]
    float* new_centers = (float*)d_out + BATCH;      // [100*512]

    char* ws = (char*)d_ws;
    float* sumf  = (float*)ws;                                   // 51200 f32
    int*   counts = (int*)(ws + NCLS * DIM * sizeof(float));     // 128 ints
    int*   order = (int*)(ws + NCLS * DIM * sizeof(float) + 128 * sizeof(int)); // NCLS*CAP ints

    hipMemsetAsync(sumf, 0, NCLS * DIM * sizeof(float), stream);
    hipMemsetAsync(counts, 0, 128 * sizeof(int), stream);

    scatter_kernel<<<(BATCH * NCLS / 4) / 256, 256, 0, stream>>>(onehot, counts, order);

    dim3 grid(CHUNKS, NCLS);
    delta_kernel<<<grid, CBLOCK, 0, stream>>>(features, centers, order, counts, sumf, result);

    finalize_kernel<<<(NCLS * DIM + 255) / 256, 256, 0, stream>>>(centers, sumf, counts, new_centers);
}

// Round 3
// 136.733 us; speedup vs baseline: 2.9223x; 1.9971x over previous
//
#include <hip/hip_runtime.h>

#define BATCH 65536
#define DIM 512
#define NCLS 100
#define ALPHA 0.5f

#define CAP 1024            // per-class slot capacity (max count ~780 for B=65536,C=100)
#define SORT_RPB 512        // rows per block in sort_kernel
#define SORT_THREADS 256
#define CHUNKS 16           // blocks per class in delta_kernel
#define CBLOCK 256          // threads per block (4 waves)
#define SLOTS (CHUNKS * (CBLOCK / 64))   // 64 wave-slots per class

// ---------------------------------------------------------------------------
// Kernel A: fused label-extract + counting-sort with LDS histogram.
// Label via exact dot-product: label[b] = sum_c onehot[b][c] * c.
// Only 100 global atomics per block (base-offset claim).
// ---------------------------------------------------------------------------
__global__ void __launch_bounds__(SORT_THREADS)
sort_kernel(const float* __restrict__ onehot,
            int* __restrict__ counts,      // [NCLS], pre-zeroed
            int* __restrict__ order) {     // [NCLS][CAP]
    __shared__ int lhist[NCLS];
    __shared__ int lbase[NCLS];
    __shared__ short llab[SORT_RPB];
    __shared__ short lrank[SORT_RPB];

    const int t = threadIdx.x;
    const int r0 = blockIdx.x * SORT_RPB;

    for (int c = t; c < NCLS; c += SORT_THREADS) lhist[c] = 0;
    __syncthreads();

    const float4* oh4 = reinterpret_cast<const float4*>(onehot);
#pragma unroll
    for (int rr = 0; rr < SORT_RPB / SORT_THREADS; ++rr) {
        const int r = rr * SORT_THREADS + t;
        const int b = r0 + r;
        float lab = 0.0f;
#pragma unroll
        for (int j = 0; j < NCLS / 4; ++j) {
            const float4 v = oh4[b * (NCLS / 4) + j];
            lab += v.x * (float)(4 * j)
                 + v.y * (float)(4 * j + 1)
                 + v.z * (float)(4 * j + 2)
                 + v.w * (float)(4 * j + 3);
        }
        const int c = (int)(lab + 0.5f);
        llab[r] = (short)c;
        lrank[r] = (short)atomicAdd(&lhist[c], 1);
    }
    __syncthreads();

    for (int c = t; c < NCLS; c += SORT_THREADS)
        lbase[c] = atomicAdd(&counts[c], lhist[c]);
    __syncthreads();

#pragma unroll
    for (int rr = 0; rr < SORT_RPB / SORT_THREADS; ++rr) {
        const int r = rr * SORT_THREADS + t;
        const int c = llab[r];
        order[c * CAP + lbase[c] + lrank[r]] = r0 + r;
    }
}

// ---------------------------------------------------------------------------
// Kernel B: fused squared-distance + per-class feature-sum.
// grid = (CHUNKS, NCLS), block = 256 (4 waves). Each wave processes rows of
// ONE class; lane owns dims [lane*8, lane*8+8). Register accumulation only.
// ---------------------------------------------------------------------------
__global__ void __launch_bounds__(CBLOCK)
delta_kernel(const float* __restrict__ features,
             const float* __restrict__ centers,
             const int* __restrict__ order,
             const int* __restrict__ counts,
             float* __restrict__ sumf,      // [NCLS][DIM], pre-zeroed
             float* __restrict__ result) {  // [BATCH], each row written once
    const int c = blockIdx.y;
    const int cnt = counts[c];
    const int lane = threadIdx.x & 63;
    const int wave = threadIdx.x >> 6;
    const int slot = blockIdx.x * (CBLOCK / 64) + wave;   // 0..SLOTS-1
    const int d = lane * 8;

    const float4 c0 = *reinterpret_cast<const float4*>(&centers[c * DIM + d]);
    const float4 c1 = *reinterpret_cast<const float4*>(&centers[c * DIM + d + 4]);
    float4 sA = make_float4(0.f, 0.f, 0.f, 0.f);
    float4 sB = make_float4(0.f, 0.f, 0.f, 0.f);

    const int* ord = &order[c * CAP];
    for (int i = slot; i < cnt; i += SLOTS) {
        const int b = ord[i];
        const float4 f0 = *reinterpret_cast<const float4*>(&features[b * DIM + d]);
        const float4 f1 = *reinterpret_cast<const float4*>(&features[b * DIM + d + 4]);

        sA.x += f0.x; sA.y += f0.y; sA.z += f0.z; sA.w += f0.w;
        sB.x += f1.x; sB.y += f1.y; sB.z += f1.z; sB.w += f1.w;

        const float dx0 = f0.x - c0.x, dy0 = f0.y - c0.y;
        const float dz0 = f0.z - c0.z, dw0 = f0.w - c0.w;
        const float dx1 = f1.x - c1.x, dy1 = f1.y - c1.y;
        const float dz1 = f1.z - c1.z, dw1 = f1.w - c1.w;
        float sq = dx0 * dx0 + dy0 * dy0 + dz0 * dz0 + dw0 * dw0
                 + dx1 * dx1 + dy1 * dy1 + dz1 * dz1 + dw1 * dw1;
#pragma unroll
        for (int m = 32; m >= 1; m >>= 1) sq += __shfl_xor(sq, m);
        if (lane == 0) result[b] = sq;
    }

    // merge this wave's partial feature-sum (8 atomics per lane, L2-resident)
    float* dst = &sumf[c * DIM + d];
    unsafeAtomicAdd(dst + 0, sA.x);
    unsafeAtomicAdd(dst + 1, sA.y);
    unsafeAtomicAdd(dst + 2, sA.z);
    unsafeAtomicAdd(dst + 3, sA.w);
    unsafeAtomicAdd(dst + 4, sB.x);
    unsafeAtomicAdd(dst + 5, sB.y);
    unsafeAtomicAdd(dst + 6, sB.z);
    unsafeAtomicAdd(dst + 7, sB.w);
}

// ---------------------------------------------------------------------------
// Kernel C: new_centers = centers - ALPHA * (cnt*center - sumf) / (cnt + 1)
// ---------------------------------------------------------------------------
__global__ void finalize_kernel(const float* __restrict__ centers,
                                const float* __restrict__ sumf,
                                const int* __restrict__ counts,
                                float* __restrict__ new_centers) {
    const int idx = blockIdx.x * blockDim.x + threadIdx.x;
    if (idx >= NCLS * DIM) return;
    const int c = idx >> 9;                 // / DIM
    const float cntf = (float)counts[c];
    const float ctr = centers[idx];
    const float delta = (cntf * ctr - sumf[idx]) / (cntf + 1.0f);
    new_centers[idx] = ctr - ALPHA * delta;
}

extern "C" void kernel_launch(void* const* d_in, const int* in_sizes, int n_in,
                              void* d_out, int out_size, void* d_ws, size_t ws_size,
                              hipStream_t stream) {
    const float* features = (const float*)d_in[0];   // [65536, 512]
    const float* onehot   = (const float*)d_in[1];   // [65536, 100]
    const float* centers  = (const float*)d_in[2];   // [100, 512]

    float* result      = (float*)d_out;              // [65536]
    float* new_centers = (float*)d_out + BATCH;      // [100*512]

    char* ws = (char*)d_ws;
    float* sumf  = (float*)ws;                                   // 51200 f32
    int*   counts = (int*)(ws + NCLS * DIM * sizeof(float));     // 128 ints
    int*   order = (int*)(ws + NCLS * DIM * sizeof(float) + 128 * sizeof(int)); // NCLS*CAP ints

    hipMemsetAsync(sumf, 0, NCLS * DIM * sizeof(float), stream);
    hipMemsetAsync(counts, 0, 128 * sizeof(int), stream);

    sort_kernel<<<BATCH / SORT_RPB, SORT_THREADS, 0, stream>>>(onehot, counts, order);

    dim3 grid(CHUNKS, NCLS);
    delta_kernel<<<grid, CBLOCK, 0, stream>>>(features, centers, order, counts, sumf, result);

    finalize_kernel<<<(NCLS * DIM + 255) / 256, 256, 0, stream>>>(centers, sumf, counts, new_centers);
}

// Round 4
// 46.238 us; speedup vs baseline: 8.6417x; 2.9572x over previous
//
#include <hip/hip_runtime.h>

#define BATCH 65536
#define DIM 512
#define NCLS 100
#define ALPHA 0.5f

#define CAP 1024            // per-class slot capacity (max count ~780 for B=65536,C=100)
#define SORT_RPB 512        // rows per block in sort_kernel
#define SORT_THREADS 256
#define CHUNKS 16           // blocks per class in delta_kernel
#define CBLOCK 256          // threads per block (4 waves)
#define SLOTS (CHUNKS * (CBLOCK / 64))   // 64 wave-slots per class

// workspace layout
#define WS_COUNTS_OFF 0
#define WS_ORDER_OFF  512
#define WS_AUX_OFF    (512 + NCLS * CAP * 4)          // part (3.27MB) or sumf (200KB)
#define WS_PART_BYTES (CHUNKS * NCLS * DIM * 4)

// ---------------------------------------------------------------------------
// Kernel A: fused label-extract + counting-sort with LDS histogram.
// Label via exact dot-product: label[b] = sum_c onehot[b][c] * c.
// Only 100 global atomics per block (base-offset claim).
// ---------------------------------------------------------------------------
__global__ void __launch_bounds__(SORT_THREADS)
sort_kernel(const float* __restrict__ onehot,
            int* __restrict__ counts,      // [NCLS], pre-zeroed
            int* __restrict__ order) {     // [NCLS][CAP]
    __shared__ int lhist[NCLS];
    __shared__ int lbase[NCLS];
    __shared__ short llab[SORT_RPB];
    __shared__ short lrank[SORT_RPB];

    const int t = threadIdx.x;
    const int r0 = blockIdx.x * SORT_RPB;

    for (int c = t; c < NCLS; c += SORT_THREADS) lhist[c] = 0;
    __syncthreads();

    const float4* oh4 = reinterpret_cast<const float4*>(onehot);
#pragma unroll
    for (int rr = 0; rr < SORT_RPB / SORT_THREADS; ++rr) {
        const int r = rr * SORT_THREADS + t;
        const int b = r0 + r;
        float lab = 0.0f;
#pragma unroll
        for (int j = 0; j < NCLS / 4; ++j) {
            const float4 v = oh4[b * (NCLS / 4) + j];
            lab += v.x * (float)(4 * j)
                 + v.y * (float)(4 * j + 1)
                 + v.z * (float)(4 * j + 2)
                 + v.w * (float)(4 * j + 3);
        }
        const int c = (int)(lab + 0.5f);
        llab[r] = (short)c;
        lrank[r] = (short)atomicAdd(&lhist[c], 1);
    }
    __syncthreads();

    for (int c = t; c < NCLS; c += SORT_THREADS)
        lbase[c] = atomicAdd(&counts[c], lhist[c]);
    __syncthreads();

#pragma unroll
    for (int rr = 0; rr < SORT_RPB / SORT_THREADS; ++rr) {
        const int r = rr * SORT_THREADS + t;
        const int c = llab[r];
        order[c * CAP + lbase[c] + lrank[r]] = r0 + r;
    }
}

// ---------------------------------------------------------------------------
// Kernel B: fused squared-distance + per-class feature-sum.
// grid = (CHUNKS, NCLS), block = 256 (4 waves), each wave handles rows of ONE
// class; lane owns dims [lane*8, lane*8+8). Register accumulation in the hot
// loop (unrolled x2 for MLP), LDS cross-wave reduce at block end, then ONE
// non-atomic 2KB streaming partial write per block (use_part mode).
// ---------------------------------------------------------------------------
__global__ void __launch_bounds__(CBLOCK)
delta_kernel(const float* __restrict__ features,
             const float* __restrict__ centers,
             const int* __restrict__ order,
             const int* __restrict__ counts,
             float* __restrict__ aux,       // part [CHUNKS][NCLS][DIM] or sumf [NCLS][DIM]
             float* __restrict__ result,    // [BATCH], each row written once
             const int use_part) {
    __shared__ float red[4][DIM];          // 8 KB

    const int c = blockIdx.y;
    const int cnt = counts[c];
    const int lane = threadIdx.x & 63;
    const int wave = threadIdx.x >> 6;
    const int slot = blockIdx.x * (CBLOCK / 64) + wave;   // 0..SLOTS-1
    const int d = lane * 8;

    const float4 c0 = *reinterpret_cast<const float4*>(&centers[c * DIM + d]);
    const float4 c1 = *reinterpret_cast<const float4*>(&centers[c * DIM + d + 4]);
    float4 sA = make_float4(0.f, 0.f, 0.f, 0.f);
    float4 sB = make_float4(0.f, 0.f, 0.f, 0.f);

    const int* ord = &order[c * CAP];
    int i = slot;
    for (; i + SLOTS < cnt; i += 2 * SLOTS) {
        const int b0 = ord[i];
        const int b1 = ord[i + SLOTS];
        const float4 f00 = *reinterpret_cast<const float4*>(&features[b0 * DIM + d]);
        const float4 f01 = *reinterpret_cast<const float4*>(&features[b0 * DIM + d + 4]);
        const float4 f10 = *reinterpret_cast<const float4*>(&features[b1 * DIM + d]);
        const float4 f11 = *reinterpret_cast<const float4*>(&features[b1 * DIM + d + 4]);

        sA.x += f00.x + f10.x; sA.y += f00.y + f10.y;
        sA.z += f00.z + f10.z; sA.w += f00.w + f10.w;
        sB.x += f01.x + f11.x; sB.y += f01.y + f11.y;
        sB.z += f01.z + f11.z; sB.w += f01.w + f11.w;

        float dx, dy, dz, dw;
        dx = f00.x - c0.x; dy = f00.y - c0.y; dz = f00.z - c0.z; dw = f00.w - c0.w;
        float sq0 = dx * dx + dy * dy + dz * dz + dw * dw;
        dx = f01.x - c1.x; dy = f01.y - c1.y; dz = f01.z - c1.z; dw = f01.w - c1.w;
        sq0 += dx * dx + dy * dy + dz * dz + dw * dw;
        dx = f10.x - c0.x; dy = f10.y - c0.y; dz = f10.z - c0.z; dw = f10.w - c0.w;
        float sq1 = dx * dx + dy * dy + dz * dz + dw * dw;
        dx = f11.x - c1.x; dy = f11.y - c1.y; dz = f11.z - c1.z; dw = f11.w - c1.w;
        sq1 += dx * dx + dy * dy + dz * dz + dw * dw;

#pragma unroll
        for (int m = 32; m >= 1; m >>= 1) {
            sq0 += __shfl_xor(sq0, m);
            sq1 += __shfl_xor(sq1, m);
        }
        if (lane == 0) {
            result[b0] = sq0;
            result[b1] = sq1;
        }
    }
    if (i < cnt) {
        const int b = ord[i];
        const float4 f0 = *reinterpret_cast<const float4*>(&features[b * DIM + d]);
        const float4 f1 = *reinterpret_cast<const float4*>(&features[b * DIM + d + 4]);
        sA.x += f0.x; sA.y += f0.y; sA.z += f0.z; sA.w += f0.w;
        sB.x += f1.x; sB.y += f1.y; sB.z += f1.z; sB.w += f1.w;
        float dx, dy, dz, dw;
        dx = f0.x - c0.x; dy = f0.y - c0.y; dz = f0.z - c0.z; dw = f0.w - c0.w;
        float sq = dx * dx + dy * dy + dz * dz + dw * dw;
        dx = f1.x - c1.x; dy = f1.y - c1.y; dz = f1.z - c1.z; dw = f1.w - c1.w;
        sq += dx * dx + dy * dy + dz * dz + dw * dw;
#pragma unroll
        for (int m = 32; m >= 1; m >>= 1) sq += __shfl_xor(sq, m);
        if (lane == 0) result[b] = sq;
    }

    // cross-wave reduction in LDS, then one streaming partial write per block
    float* r = &red[wave][d];
    r[0] = sA.x; r[1] = sA.y; r[2] = sA.z; r[3] = sA.w;
    r[4] = sB.x; r[5] = sB.y; r[6] = sB.z; r[7] = sB.w;
    __syncthreads();

    const int t = threadIdx.x;
    if (use_part) {
        float* dst = &aux[(blockIdx.x * NCLS + c) * DIM];
#pragma unroll
        for (int k = 0; k < DIM / CBLOCK; ++k) {
            const int dd = k * CBLOCK + t;
            dst[dd] = red[0][dd] + red[1][dd] + red[2][dd] + red[3][dd];
        }
    } else {
#pragma unroll
        for (int k = 0; k < DIM / CBLOCK; ++k) {
            const int dd = k * CBLOCK + t;
            const float s = red[0][dd] + red[1][dd] + red[2][dd] + red[3][dd];
            unsafeAtomicAdd(&aux[c * DIM + dd], s);
        }
    }
}

// ---------------------------------------------------------------------------
// Kernel C: new_centers = centers - ALPHA * (cnt*center - sumf) / (cnt + 1)
// ---------------------------------------------------------------------------
__global__ void finalize_kernel(const float* __restrict__ centers,
                                const float* __restrict__ aux,
                                const int* __restrict__ counts,
                                float* __restrict__ new_centers,
                                const int use_part) {
    const int idx = blockIdx.x * blockDim.x + threadIdx.x;
    if (idx >= NCLS * DIM) return;
    float s;
    if (use_part) {
        s = 0.0f;
#pragma unroll
        for (int k = 0; k < CHUNKS; ++k) s += aux[k * NCLS * DIM + idx];
    } else {
        s = aux[idx];
    }
    const int c = idx >> 9;                 // / DIM
    const float cntf = (float)counts[c];
    const float ctr = centers[idx];
    const float delta = (cntf * ctr - s) / (cntf + 1.0f);
    new_centers[idx] = ctr - ALPHA * delta;
}

extern "C" void kernel_launch(void* const* d_in, const int* in_sizes, int n_in,
                              void* d_out, int out_size, void* d_ws, size_t ws_size,
                              hipStream_t stream) {
    const float* features = (const float*)d_in[0];   // [65536, 512]
    const float* onehot   = (const float*)d_in[1];   // [65536, 100]
    const float* centers  = (const float*)d_in[2];   // [100, 512]

    float* result      = (float*)d_out;              // [65536]
    float* new_centers = (float*)d_out + BATCH;      // [100*512]

    char* ws = (char*)d_ws;
    int*   counts = (int*)(ws + WS_COUNTS_OFF);      // 128 ints
    int*   order  = (int*)(ws + WS_ORDER_OFF);       // NCLS*CAP ints
    float* aux    = (float*)(ws + WS_AUX_OFF);       // part or sumf

    const int use_part = (ws_size >= (size_t)WS_AUX_OFF + WS_PART_BYTES) ? 1 : 0;

    hipMemsetAsync(counts, 0, 128 * sizeof(int), stream);
    if (!use_part)
        hipMemsetAsync(aux, 0, NCLS * DIM * sizeof(float), stream);

    sort_kernel<<<BATCH / SORT_RPB, SORT_THREADS, 0, stream>>>(onehot, counts, order);

    dim3 grid(CHUNKS, NCLS);
    delta_kernel<<<grid, CBLOCK, 0, stream>>>(features, centers, order, counts, aux, result, use_part);

    finalize_kernel<<<(NCLS * DIM + 255) / 256, 256, 0, stream>>>(centers, aux, counts, new_centers, use_part);
}